// Round 1
// 694.178 us; speedup vs baseline: 1.0351x; 1.0351x over previous
//
#include <hip/hip_runtime.h>
#include <hip/hip_bf16.h>

typedef __hip_bfloat16 bf16;
typedef __attribute__((ext_vector_type(8)))  short  short8;
typedef __attribute__((ext_vector_type(16))) float  floatx16;

#define HW 65536   // 256*256

__device__ __forceinline__ float b2f(bf16 v){ return __bfloat162float(v); }
__device__ __forceinline__ bf16  f2b(float v){ return __float2bfloat16(v); }
__device__ __forceinline__ unsigned short f2bu(float v){
  union { bf16 h; unsigned short u; } cv; cv.h = __float2bfloat16(v); return cv.u;
}
__device__ __forceinline__ float bu2f(unsigned short u){
  union { unsigned u; float f; } cv; cv.u = ((unsigned)u) << 16; return cv.f;
}

// ---- fused setup: weight prep for both 3x3 convs + lang logits ----
// blocks 0..143   : w_d3 -> wb3 granules
// blocks 144..287 : w_d1 -> wb1 granules
// blocks 288..295 : lang raw logits per n (log_softmax LSE cancels downstream)
__global__ __launch_bounds__(256) void setup_kernel(
    const float* __restrict__ w_d3, const float* __restrict__ w_d1,
    bf16* __restrict__ wb3, bf16* __restrict__ wb1,
    const float* __restrict__ action,
    const float* __restrict__ w_a1, const float* __restrict__ b_a1,
    const float* __restrict__ w_a2, const float* __restrict__ b_a2,
    float* __restrict__ lang){
  int b = blockIdx.x;
  if (b < 288){
    const float* w = (b < 144) ? w_d3 : w_d1;
    bf16* wb = (b < 144) ? wb3 : wb1;
    int i = (b < 144 ? b : b - 144)*256 + threadIdx.x;
    if (i >= 36864) return;
    int j    = i & 7;
    int gran = i >> 3;
    int oc   = gran & 63;
    int rest = gran >> 6;          // (t*4+ks)*2+half
    int half = rest & 1;
    int ks   = (rest >> 1) & 3;
    int t    = rest >> 3;
    int e  = ks*16 + half*8 + j;
    int ki = t / 3, kj = t - ki*3;
    wb[i] = f2b(w[(oc*64 + e)*9 + ki*3 + kj]);
  } else {
    int n = b - 288;
    int t = threadIdx.x;
    __shared__ float part[256];
    __shared__ float hid[64];
    int d = t & 63, q = t >> 6;
    const float* ar = action + n*256;
    float a = 0.f;
    #pragma unroll 8
    for (int i = q*64; i < q*64 + 64; i++) a += ar[i]*w_a1[i*64 + d];
    part[t] = a;
    __syncthreads();
    if (t < 64)
      hid[t] = fmaxf(b_a1[t] + part[t] + part[64+t] + part[128+t] + part[192+t], 0.f);
    __syncthreads();
    if (t < 49){
      float l = b_a2[t];
      #pragma unroll 8
      for (int j2 = 0; j2 < 64; j2++) l += hid[j2]*w_a2[j2*49 + t];
      lang[n*49 + t] = l;    // unnormalized: per-n LSE cancels in final log_softmax
    }
  }
}

// ---- maxpool 2x2 + 1x1 conv 32->64 + relu; x,h1 written NHWC ----
__global__ __launch_bounds__(256) void pool_in_kernel(
    const float* __restrict__ sm, const float* __restrict__ w_in,
    const float* __restrict__ b_in, float* __restrict__ x, bf16* __restrict__ h1){
  int p = blockIdx.x*256 + threadIdx.x;
  int n = p >> 16; int ij = p & 65535; int i = ij >> 8; int j = ij & 255;
  const float* smn = sm + ((long)n << 23);   // n*32*512*512
  float xv[32];
  #pragma unroll
  for (int d = 0; d < 32; d++){
    long base = ((long)(d*512 + 2*i) << 9) + 2*j;
    float2 p0 = *reinterpret_cast<const float2*>(smn + base);
    float2 p1 = *reinterpret_cast<const float2*>(smn + base + 512);
    xv[d] = fmaxf(fmaxf(p0.x, p0.y), fmaxf(p1.x, p1.y));
  }
  float4* xo = reinterpret_cast<float4*>(x + ((long)p << 5));
  #pragma unroll
  for (int q = 0; q < 8; q++)
    xo[q] = make_float4(xv[4*q], xv[4*q+1], xv[4*q+2], xv[4*q+3]);
  unsigned ow[32];
  #pragma unroll 4
  for (int c = 0; c < 64; c += 2){
    float a0 = b_in[c], a1 = b_in[c+1];
    #pragma unroll
    for (int d = 0; d < 32; d++){
      a0 += xv[d]*w_in[c*32+d];
      a1 += xv[d]*w_in[(c+1)*32+d];
    }
    ow[c>>1] = ((unsigned)f2bu(fmaxf(a1,0.f)) << 16) | f2bu(fmaxf(a0,0.f));
  }
  uint4* ho = reinterpret_cast<uint4*>((char*)h1 + ((long)p << 7));
  #pragma unroll
  for (int q = 0; q < 8; q++)
    ho[q] = make_uint4(ow[4*q], ow[4*q+1], ow[4*q+2], ow[4*q+3]);
}

// ---- 3x3 conv 64->64 + relu via MFMA implicit GEMM; NHWC in/out ----
// block = 256 thr (4 waves), 16x16 spatial tile, M=256 pix, N=64 oc, K=576.
// v2: each wave owns m-tile pair {wv*2, wv*2+1} and BOTH n-tiles (all 64 oc):
//     each A-fragment ds_read feeds 2 MFMAs -> LDS read demand halved
//     (was the 25%-MfmaUtil cap: 1 ds_read_b128 per MFMA = 512 B/cyc demand
//      vs 128 B/cyc LDS; now capped ~50%). B granules come from L1/L2.
template<int DIL>
__global__ __launch_bounds__(256) void conv3x3_mfma(
    const bf16* __restrict__ hin, const bf16* __restrict__ wb,
    const float* __restrict__ bias, bf16* __restrict__ hout){
  constexpr int R = 16 + 2*DIL, C = 16 + 2*DIL, NPIX = R*C;
  __shared__ __align__(16) char tile[NPIX*128];   // [pix][64e] bf16, XOR-swizzled granules
  int b = blockIdx.x;
  int n = b >> 8; int tb = b & 255;
  int i0 = (tb >> 4) << 4, j0 = (tb & 15) << 4;
  int tid = threadIdx.x;
  const bf16* hn = hin + ((long)n << 22);  // n*HW*64
  for (int s = tid; s < NPIX*8; s += 256){
    int pix = s >> 3, g = s & 7;
    int r = pix / C, c = pix - r*C;
    int gi = i0 - DIL + r, gj = j0 - DIL + c;
    uint4 v = make_uint4(0u,0u,0u,0u);
    if (gi >= 0 && gi < 256 && gj >= 0 && gj < 256)
      v = *reinterpret_cast<const uint4*>(hn + (((long)((gi<<8) + gj)) << 6) + (g<<3));
    *reinterpret_cast<uint4*>(tile + pix*128 + ((g ^ (pix & 7)) << 4)) = v;
  }
  __syncthreads();
  int lane = tid & 63, wv = tid >> 6;
  int l31 = lane & 31, half = lane >> 5;
  floatx16 acc[2][2];
  #pragma unroll
  for (int m2 = 0; m2 < 2; m2++){
    acc[m2][0] = (floatx16)(0.0f);
    acc[m2][1] = (floatx16)(0.0f);
  }
  int prr[2], pcc[2];
  #pragma unroll
  for (int m2 = 0; m2 < 2; m2++){
    int pidx = (wv*2 + m2)*32 + l31;
    prr[m2] = pidx >> 4; pcc[m2] = pidx & 15;
  }
  const char* wbc = reinterpret_cast<const char*>(wb);
  for (int t = 0; t < 9; t++){
    int ki = t / 3, kj = t - ki*3;
    int pp[2];
    #pragma unroll
    for (int m2 = 0; m2 < 2; m2++)
      pp[m2] = (prr[m2] + ki*DIL)*C + (pcc[m2] + kj*DIL);
    short8 bfr[4][2];
    #pragma unroll
    for (int ks = 0; ks < 4; ks++){
      #pragma unroll
      for (int nt = 0; nt < 2; nt++)
        bfr[ks][nt] = *reinterpret_cast<const short8*>(
            wbc + ((((t*4 + ks)*2 + half)*64 + nt*32 + l31) << 4));
    }
    #pragma unroll
    for (int ks = 0; ks < 4; ks++){
      #pragma unroll
      for (int m2 = 0; m2 < 2; m2++){
        short8 afrag = *reinterpret_cast<const short8*>(
            tile + pp[m2]*128 + (((ks*2 + half) ^ (pp[m2] & 7)) << 4));
        acc[m2][0] = __builtin_amdgcn_mfma_f32_32x32x16_bf16(afrag, bfr[ks][0], acc[m2][0], 0, 0, 0);
        acc[m2][1] = __builtin_amdgcn_mfma_f32_32x32x16_bf16(afrag, bfr[ks][1], acc[m2][1], 0, 0, 0);
      }
    }
  }
  float bv0 = bias[l31], bv1 = bias[32 + l31];
  bf16* ho = hout + ((long)n << 22);
  #pragma unroll
  for (int m2 = 0; m2 < 2; m2++){
    #pragma unroll
    for (int reg = 0; reg < 16; reg++){
      int row = (reg & 3) + 8*(reg >> 2) + 4*half;     // C/D layout, 32x32 [m74/m101]
      int pidx = (wv*2 + m2)*32 + row;
      int pr = pidx >> 4, pc = pidx & 15;
      long off = ((long)(((i0+pr)<<8) + (j0+pc))) << 6;
      ho[off + l31]      = f2b(fmaxf(acc[m2][0][reg] + bv0, 0.f));
      ho[off + 32 + l31] = f2b(fmaxf(acc[m2][1][reg] + bv1, 0.f));
    }
  }
}

// ---- residual 1x1 64->32, 1x1 32->49 + lang, fused log_softmax; NHWC in, lk NCHW out
__global__ __launch_bounds__(256) void out_motion_kernel(
    const bf16* __restrict__ h3, const float* __restrict__ x,
    const float* __restrict__ w_out, const float* __restrict__ b_out,
    const float* __restrict__ w_k, const float* __restrict__ b_k,
    const float* __restrict__ lang, float* __restrict__ lk){
  int p = blockIdx.x*256 + threadIdx.x;
  int n = p >> 16; int ij = p & 65535;
  float hv[64];
  const uint4* hp = reinterpret_cast<const uint4*>((const char*)h3 + ((long)p << 7));
  #pragma unroll
  for (int q = 0; q < 8; q++){
    uint4 u = hp[q];
    unsigned uu[4] = {u.x, u.y, u.z, u.w};
    #pragma unroll
    for (int k = 0; k < 4; k++){
      hv[q*8 + 2*k]   = bu2f((unsigned short)(uu[k] & 0xffffu));
      hv[q*8 + 2*k+1] = bu2f((unsigned short)(uu[k] >> 16));
    }
  }
  float o[32];
  const float4* xp = reinterpret_cast<const float4*>(x + ((long)p << 5));
  #pragma unroll
  for (int q = 0; q < 8; q++){
    float4 tq = xp[q];
    o[4*q] = tq.x; o[4*q+1] = tq.y; o[4*q+2] = tq.z; o[4*q+3] = tq.w;
  }
  #pragma unroll 4
  for (int d = 0; d < 32; d++){
    float acc = b_out[d];
    #pragma unroll
    for (int e = 0; e < 64; e++) acc += hv[e]*w_out[d*64+e];
    o[d] += acc;
  }
  float lg[49]; float m = -1e30f;
  #pragma unroll 7
  for (int k = 0; k < 49; k++){
    float acc = b_k[k] + lang[n*49+k];
    #pragma unroll
    for (int d = 0; d < 32; d++) acc += o[d]*w_k[k*32+d];
    lg[k] = acc; m = fmaxf(m, acc);
  }
  float s = 0.f;
  #pragma unroll
  for (int k = 0; k < 49; k++) s += __expf(lg[k]-m);
  float lse = m + __logf(s);
  #pragma unroll
  for (int k = 0; k < 49; k++) lk[(long)n*49*HW + (long)k*HW + ij] = lg[k] - lse;
}

// ---- 7x7 gather logsumexp (f32 output) ----
__global__ __launch_bounds__(256) void gather_lse_kernel(
    const float* __restrict__ lb, const float* __restrict__ lk, float* __restrict__ out){
  int p = blockIdx.x*256 + threadIdx.x;
  int n = p >> 16; int ij = p & 65535; int i = ij >> 8; int j = ij & 255;
  const float* lkn = lk + (long)n*49*HW;
  float v[49]; float m = -1e30f;
  #pragma unroll
  for (int ki = 0; ki < 7; ki++){
    int h = i + 3 - ki;
    bool hok = (h >= 0 && h < 256);
    #pragma unroll
    for (int kj = 0; kj < 7; kj++){
      int w = j + 3 - kj;
      float val = -1e30f;
      if (hok && w >= 0 && w < 256){
        int q = h*256 + w;
        val = lb[n*HW + q] + lkn[(ki*7+kj)*HW + q];
      }
      v[ki*7+kj] = val; m = fmaxf(m, val);
    }
  }
  float s = 0.f;
  #pragma unroll
  for (int t = 0; t < 49; t++) s += __expf(v[t]-m);
  out[p] = m + __logf(s);
}

// ---- launch ----
// ws layout (bytes):
//   x    f32 NHWC [8][65536][32] @ 0            (67,108,864)
//   h1   bf16 NHWC [8][65536][64] @  67,108,864 (67,108,864)
//   h2   bf16 NHWC               @ 134,217,728  (67,108,864)  dead after conv<1>
//   lk   f32  [8][49][65536]     @ 134,217,728  (102,760,448) overlaps dead h2
//   lang f32  [8][49]            @ 236,978,176  (1,792)
//   wb3  bf16 granules           @ 236,979,968  (73,728)
//   wb1  bf16 granules           @ 237,053,696  (73,728)
extern "C" void kernel_launch(void* const* d_in, const int* in_sizes, int n_in,
                              void* d_out, int out_size, void* d_ws, size_t ws_size,
                              hipStream_t stream) {
  (void)in_sizes; (void)n_in; (void)out_size; (void)ws_size;
  const float* lb    = (const float*)d_in[0];
  const float* sm    = (const float*)d_in[1];
  const float* act   = (const float*)d_in[2];
  const float* w_in  = (const float*)d_in[3];
  const float* b_in  = (const float*)d_in[4];
  const float* w_d3  = (const float*)d_in[5];
  const float* b_d3  = (const float*)d_in[6];
  const float* w_d1  = (const float*)d_in[7];
  const float* b_d1  = (const float*)d_in[8];
  const float* w_out = (const float*)d_in[9];
  const float* b_out = (const float*)d_in[10];
  const float* w_k   = (const float*)d_in[11];
  const float* b_k   = (const float*)d_in[12];
  const float* w_a1  = (const float*)d_in[13];
  const float* b_a1  = (const float*)d_in[14];
  const float* w_a2  = (const float*)d_in[15];
  const float* b_a2  = (const float*)d_in[16];
  float* out = (float*)d_out;

  char* ws = (char*)d_ws;
  float* x    = (float*)(ws + 0);
  bf16*  h1   = (bf16*) (ws + 67108864);
  bf16*  h2   = (bf16*) (ws + 134217728);
  float* lk   = (float*)(ws + 134217728);
  float* lang = (float*)(ws + 236978176);
  bf16*  wb3  = (bf16*) (ws + 236979968);
  bf16*  wb1  = (bf16*) (ws + 237053696);

  setup_kernel<<<296, 256, 0, stream>>>(w_d3, w_d1, wb3, wb1,
                                        act, w_a1, b_a1, w_a2, b_a2, lang);
  pool_in_kernel<<<2048, 256, 0, stream>>>(sm, w_in, b_in, x, h1);
  conv3x3_mfma<3><<<2048, 256, 0, stream>>>(h1, wb3, b_d3, h2);
  conv3x3_mfma<1><<<2048, 256, 0, stream>>>(h2, wb1, b_d1, h1);
  out_motion_kernel<<<2048, 256, 0, stream>>>(h1, x, w_out, b_out,
                                              w_k, b_k, lang, lk);
  gather_lse_kernel<<<2048, 256, 0, stream>>>(lb, lk, out);
}

// Round 2
// 679.474 us; speedup vs baseline: 1.0575x; 1.0216x over previous
//
#include <hip/hip_runtime.h>
#include <hip/hip_bf16.h>

typedef __hip_bfloat16 bf16;
typedef _Float16 fp16;
typedef __attribute__((ext_vector_type(8)))  short  short8;
typedef __attribute__((ext_vector_type(16))) float  floatx16;

#define HW 65536   // 256*256

__device__ __forceinline__ float b2f(bf16 v){ return __bfloat162float(v); }
__device__ __forceinline__ bf16  f2b(float v){ return __float2bfloat16(v); }
__device__ __forceinline__ unsigned short f2bu(float v){
  union { bf16 h; unsigned short u; } cv; cv.h = __float2bfloat16(v); return cv.u;
}
__device__ __forceinline__ float bu2f(unsigned short u){
  union { unsigned u; float f; } cv; cv.u = ((unsigned)u) << 16; return cv.f;
}
__device__ __forceinline__ unsigned short f2hu(float v){
  union { fp16 h; unsigned short u; } cv; cv.h = (fp16)v; return cv.u;
}
__device__ __forceinline__ float hu2f(unsigned short u){
  union { fp16 h; unsigned short u; } cv; cv.u = u; return (float)cv.h;
}

// ---- fused setup: weight prep for both 3x3 convs + lang logits ----
// blocks 0..143   : w_d3 -> wb3 granules
// blocks 144..287 : w_d1 -> wb1 granules
// blocks 288..295 : lang raw logits per n (log_softmax LSE cancels downstream)
__global__ __launch_bounds__(256) void setup_kernel(
    const float* __restrict__ w_d3, const float* __restrict__ w_d1,
    bf16* __restrict__ wb3, bf16* __restrict__ wb1,
    const float* __restrict__ action,
    const float* __restrict__ w_a1, const float* __restrict__ b_a1,
    const float* __restrict__ w_a2, const float* __restrict__ b_a2,
    float* __restrict__ lang){
  int b = blockIdx.x;
  if (b < 288){
    const float* w = (b < 144) ? w_d3 : w_d1;
    bf16* wb = (b < 144) ? wb3 : wb1;
    int i = (b < 144 ? b : b - 144)*256 + threadIdx.x;
    if (i >= 36864) return;
    int j    = i & 7;
    int gran = i >> 3;
    int oc   = gran & 63;
    int rest = gran >> 6;          // (t*4+ks)*2+half
    int half = rest & 1;
    int ks   = (rest >> 1) & 3;
    int t    = rest >> 3;
    int e  = ks*16 + half*8 + j;
    int ki = t / 3, kj = t - ki*3;
    wb[i] = f2b(w[(oc*64 + e)*9 + ki*3 + kj]);
  } else {
    int n = b - 288;
    int t = threadIdx.x;
    __shared__ float part[256];
    __shared__ float hid[64];
    int d = t & 63, q = t >> 6;
    const float* ar = action + n*256;
    float a = 0.f;
    #pragma unroll 8
    for (int i = q*64; i < q*64 + 64; i++) a += ar[i]*w_a1[i*64 + d];
    part[t] = a;
    __syncthreads();
    if (t < 64)
      hid[t] = fmaxf(b_a1[t] + part[t] + part[64+t] + part[128+t] + part[192+t], 0.f);
    __syncthreads();
    if (t < 49){
      float l = b_a2[t];
      #pragma unroll 8
      for (int j2 = 0; j2 < 64; j2++) l += hid[j2]*w_a2[j2*49 + t];
      lang[n*49 + t] = l;    // unnormalized: per-n LSE cancels in final log_softmax
    }
  }
}

// ---- maxpool 2x2 + 1x1 conv 32->64 + relu; x fp16 NHWC, h1 bf16 NHWC ----
__global__ __launch_bounds__(256) void pool_in_kernel(
    const float* __restrict__ sm, const float* __restrict__ w_in,
    const float* __restrict__ b_in, fp16* __restrict__ x, bf16* __restrict__ h1){
  int p = blockIdx.x*256 + threadIdx.x;
  int n = p >> 16; int ij = p & 65535; int i = ij >> 8; int j = ij & 255;
  const float* smn = sm + ((long)n << 23);   // n*32*512*512
  float xv[32];
  #pragma unroll
  for (int d = 0; d < 32; d++){
    long base = ((long)(d*512 + 2*i) << 9) + 2*j;
    float2 p0 = *reinterpret_cast<const float2*>(smn + base);
    float2 p1 = *reinterpret_cast<const float2*>(smn + base + 512);
    xv[d] = fmaxf(fmaxf(p0.x, p0.y), fmaxf(p1.x, p1.y));
  }
  unsigned xw[16];
  #pragma unroll
  for (int q = 0; q < 16; q++)
    xw[q] = ((unsigned)f2hu(xv[2*q+1]) << 16) | f2hu(xv[2*q]);
  uint4* xo = reinterpret_cast<uint4*>((char*)x + ((long)p << 6));  // 64 B/pixel
  #pragma unroll
  for (int q = 0; q < 4; q++)
    xo[q] = make_uint4(xw[4*q], xw[4*q+1], xw[4*q+2], xw[4*q+3]);
  unsigned ow[32];
  #pragma unroll 4
  for (int c = 0; c < 64; c += 2){
    float a0 = b_in[c], a1 = b_in[c+1];
    #pragma unroll
    for (int d = 0; d < 32; d++){
      a0 += xv[d]*w_in[c*32+d];
      a1 += xv[d]*w_in[(c+1)*32+d];
    }
    ow[c>>1] = ((unsigned)f2bu(fmaxf(a1,0.f)) << 16) | f2bu(fmaxf(a0,0.f));
  }
  uint4* ho = reinterpret_cast<uint4*>((char*)h1 + ((long)p << 7));
  #pragma unroll
  for (int q = 0; q < 8; q++)
    ho[q] = make_uint4(ow[4*q], ow[4*q+1], ow[4*q+2], ow[4*q+3]);
}

// ---- 3x3 conv 64->64 + relu via MFMA implicit GEMM; NHWC in/out ----
// block = 256 thr (4 waves), 16x16 spatial tile, M=256 pix, N=64 oc, K=576.
// Each wave owns m-tile pair {wv*2, wv*2+1} and BOTH n-tiles (all 64 oc):
// each A-fragment ds_read feeds 2 MFMAs. XCD swizzle: n = b&7 so each XCD's
// private L2 owns one image -> halo rows/cols (tb-1, tb-16) are L2 hits.
template<int DIL>
__global__ __launch_bounds__(256) void conv3x3_mfma(
    const bf16* __restrict__ hin, const bf16* __restrict__ wb,
    const float* __restrict__ bias, bf16* __restrict__ hout){
  constexpr int R = 16 + 2*DIL, C = 16 + 2*DIL, NPIX = R*C;
  __shared__ __align__(16) char tile[NPIX*128];   // [pix][64e] bf16, XOR-swizzled granules
  int b = blockIdx.x;
  int n = b & 7; int tb = b >> 3;                 // XCD-aware: image n pinned to XCD
  int i0 = (tb >> 4) << 4, j0 = (tb & 15) << 4;
  int tid = threadIdx.x;
  const bf16* hn = hin + ((long)n << 22);  // n*HW*64
  for (int s = tid; s < NPIX*8; s += 256){
    int pix = s >> 3, g = s & 7;
    int r = pix / C, c = pix - r*C;
    int gi = i0 - DIL + r, gj = j0 - DIL + c;
    uint4 v = make_uint4(0u,0u,0u,0u);
    if (gi >= 0 && gi < 256 && gj >= 0 && gj < 256)
      v = *reinterpret_cast<const uint4*>(hn + (((long)((gi<<8) + gj)) << 6) + (g<<3));
    *reinterpret_cast<uint4*>(tile + pix*128 + ((g ^ (pix & 7)) << 4)) = v;
  }
  __syncthreads();
  int lane = tid & 63, wv = tid >> 6;
  int l31 = lane & 31, half = lane >> 5;
  floatx16 acc[2][2];
  #pragma unroll
  for (int m2 = 0; m2 < 2; m2++){
    acc[m2][0] = (floatx16)(0.0f);
    acc[m2][1] = (floatx16)(0.0f);
  }
  int prr[2], pcc[2];
  #pragma unroll
  for (int m2 = 0; m2 < 2; m2++){
    int pidx = (wv*2 + m2)*32 + l31;
    prr[m2] = pidx >> 4; pcc[m2] = pidx & 15;
  }
  const char* wbc = reinterpret_cast<const char*>(wb);
  for (int t = 0; t < 9; t++){
    int ki = t / 3, kj = t - ki*3;
    int pp[2];
    #pragma unroll
    for (int m2 = 0; m2 < 2; m2++)
      pp[m2] = (prr[m2] + ki*DIL)*C + (pcc[m2] + kj*DIL);
    short8 bfr[4][2];
    #pragma unroll
    for (int ks = 0; ks < 4; ks++){
      #pragma unroll
      for (int nt = 0; nt < 2; nt++)
        bfr[ks][nt] = *reinterpret_cast<const short8*>(
            wbc + ((((t*4 + ks)*2 + half)*64 + nt*32 + l31) << 4));
    }
    #pragma unroll
    for (int ks = 0; ks < 4; ks++){
      #pragma unroll
      for (int m2 = 0; m2 < 2; m2++){
        short8 afrag = *reinterpret_cast<const short8*>(
            tile + pp[m2]*128 + (((ks*2 + half) ^ (pp[m2] & 7)) << 4));
        acc[m2][0] = __builtin_amdgcn_mfma_f32_32x32x16_bf16(afrag, bfr[ks][0], acc[m2][0], 0, 0, 0);
        acc[m2][1] = __builtin_amdgcn_mfma_f32_32x32x16_bf16(afrag, bfr[ks][1], acc[m2][1], 0, 0, 0);
      }
    }
  }
  float bv0 = bias[l31], bv1 = bias[32 + l31];
  bf16* ho = hout + ((long)n << 22);
  #pragma unroll
  for (int m2 = 0; m2 < 2; m2++){
    #pragma unroll
    for (int reg = 0; reg < 16; reg++){
      int row = (reg & 3) + 8*(reg >> 2) + 4*half;     // C/D layout, 32x32 [m74/m101]
      int pidx = (wv*2 + m2)*32 + row;
      int pr = pidx >> 4, pc = pidx & 15;
      long off = ((long)(((i0+pr)<<8) + (j0+pc))) << 6;
      ho[off + l31]      = f2b(fmaxf(acc[m2][0][reg] + bv0, 0.f));
      ho[off + 32 + l31] = f2b(fmaxf(acc[m2][1][reg] + bv1, 0.f));
    }
  }
}

// ---- residual 1x1 64->32, 1x1 32->49 + lang, fused log_softmax; NHWC in, lk fp16 NCHW out
__global__ __launch_bounds__(256) void out_motion_kernel(
    const bf16* __restrict__ h3, const fp16* __restrict__ x,
    const float* __restrict__ w_out, const float* __restrict__ b_out,
    const float* __restrict__ w_k, const float* __restrict__ b_k,
    const float* __restrict__ lang, fp16* __restrict__ lk){
  int p = blockIdx.x*256 + threadIdx.x;
  int n = p >> 16; int ij = p & 65535;
  float hv[64];
  const uint4* hp = reinterpret_cast<const uint4*>((const char*)h3 + ((long)p << 7));
  #pragma unroll
  for (int q = 0; q < 8; q++){
    uint4 u = hp[q];
    unsigned uu[4] = {u.x, u.y, u.z, u.w};
    #pragma unroll
    for (int k = 0; k < 4; k++){
      hv[q*8 + 2*k]   = bu2f((unsigned short)(uu[k] & 0xffffu));
      hv[q*8 + 2*k+1] = bu2f((unsigned short)(uu[k] >> 16));
    }
  }
  float o[32];
  const uint4* xp = reinterpret_cast<const uint4*>((const char*)x + ((long)p << 6));
  #pragma unroll
  for (int q = 0; q < 4; q++){
    uint4 u = xp[q];
    unsigned uu[4] = {u.x, u.y, u.z, u.w};
    #pragma unroll
    for (int k = 0; k < 4; k++){
      o[q*8 + 2*k]   = hu2f((unsigned short)(uu[k] & 0xffffu));
      o[q*8 + 2*k+1] = hu2f((unsigned short)(uu[k] >> 16));
    }
  }
  #pragma unroll 4
  for (int d = 0; d < 32; d++){
    float acc = b_out[d];
    #pragma unroll
    for (int e = 0; e < 64; e++) acc += hv[e]*w_out[d*64+e];
    o[d] += acc;
  }
  float lg[49]; float m = -1e30f;
  #pragma unroll 7
  for (int k = 0; k < 49; k++){
    float acc = b_k[k] + lang[n*49+k];
    #pragma unroll
    for (int d = 0; d < 32; d++) acc += o[d]*w_k[k*32+d];
    lg[k] = acc; m = fmaxf(m, acc);
  }
  float s = 0.f;
  #pragma unroll
  for (int k = 0; k < 49; k++) s += __expf(lg[k]-m);
  float lse = m + __logf(s);
  #pragma unroll
  for (int k = 0; k < 49; k++)
    lk[(long)n*49*HW + (long)k*HW + ij] = (fp16)(lg[k] - lse);
}

// ---- 7x7 gather logsumexp (f32 output); lk fp16, XCD-swizzled rows ----
__global__ __launch_bounds__(256) void gather_lse_kernel(
    const float* __restrict__ lb, const fp16* __restrict__ lk, float* __restrict__ out){
  int b = blockIdx.x;
  int n = b & 7;                         // XCD-aware: image n pinned to XCD
  int ij = ((b >> 3) << 8) | threadIdx.x;
  int i = ij >> 8; int j = ij & 255;
  const fp16* lkn = lk + (long)n*49*HW;
  float v[49]; float m = -1e30f;
  #pragma unroll
  for (int ki = 0; ki < 7; ki++){
    int h = i + 3 - ki;
    bool hok = (h >= 0 && h < 256);
    #pragma unroll
    for (int kj = 0; kj < 7; kj++){
      int w = j + 3 - kj;
      float val = -1e30f;
      if (hok && w >= 0 && w < 256){
        int q = h*256 + w;
        val = lb[n*HW + q] + (float)lkn[(ki*7+kj)*HW + q];
      }
      v[ki*7+kj] = val; m = fmaxf(m, val);
    }
  }
  float s = 0.f;
  #pragma unroll
  for (int t = 0; t < 49; t++) s += __expf(v[t]-m);
  out[n*HW + ij] = m + __logf(s);
}

// ---- launch ----
// ws layout (bytes):
//   x    fp16 NHWC [8][65536][32] @ 0           (33,554,432)
//   h1   bf16 NHWC [8][65536][64] @  67,108,864 (67,108,864)
//   h2   bf16 NHWC               @ 134,217,728  (67,108,864)  dead after conv<1>
//   lk   fp16 [8][49][65536]     @ 134,217,728  (51,380,224)  overlaps dead h2
//   lang f32  [8][49]            @ 236,978,176  (1,792)
//   wb3  bf16 granules           @ 236,979,968  (73,728)
//   wb1  bf16 granules           @ 237,053,696  (73,728)
extern "C" void kernel_launch(void* const* d_in, const int* in_sizes, int n_in,
                              void* d_out, int out_size, void* d_ws, size_t ws_size,
                              hipStream_t stream) {
  (void)in_sizes; (void)n_in; (void)out_size; (void)ws_size;
  const float* lb    = (const float*)d_in[0];
  const float* sm    = (const float*)d_in[1];
  const float* act   = (const float*)d_in[2];
  const float* w_in  = (const float*)d_in[3];
  const float* b_in  = (const float*)d_in[4];
  const float* w_d3  = (const float*)d_in[5];
  const float* b_d3  = (const float*)d_in[6];
  const float* w_d1  = (const float*)d_in[7];
  const float* b_d1  = (const float*)d_in[8];
  const float* w_out = (const float*)d_in[9];
  const float* b_out = (const float*)d_in[10];
  const float* w_k   = (const float*)d_in[11];
  const float* b_k   = (const float*)d_in[12];
  const float* w_a1  = (const float*)d_in[13];
  const float* b_a1  = (const float*)d_in[14];
  const float* w_a2  = (const float*)d_in[15];
  const float* b_a2  = (const float*)d_in[16];
  float* out = (float*)d_out;

  char* ws = (char*)d_ws;
  fp16*  x    = (fp16*) (ws + 0);
  bf16*  h1   = (bf16*) (ws + 67108864);
  bf16*  h2   = (bf16*) (ws + 134217728);
  fp16*  lk   = (fp16*) (ws + 134217728);
  float* lang = (float*)(ws + 236978176);
  bf16*  wb3  = (bf16*) (ws + 236979968);
  bf16*  wb1  = (bf16*) (ws + 237053696);

  setup_kernel<<<296, 256, 0, stream>>>(w_d3, w_d1, wb3, wb1,
                                        act, w_a1, b_a1, w_a2, b_a2, lang);
  pool_in_kernel<<<2048, 256, 0, stream>>>(sm, w_in, b_in, x, h1);
  conv3x3_mfma<3><<<2048, 256, 0, stream>>>(h1, wb3, b_d3, h2);
  conv3x3_mfma<1><<<2048, 256, 0, stream>>>(h2, wb1, b_d1, h1);
  out_motion_kernel<<<2048, 256, 0, stream>>>(h1, x, w_out, b_out,
                                              w_k, b_k, lang, lk);
  gather_lse_kernel<<<2048, 256, 0, stream>>>(lb, lk, out);
}

// Round 3
// 677.852 us; speedup vs baseline: 1.0601x; 1.0024x over previous
//
#include <hip/hip_runtime.h>
#include <hip/hip_bf16.h>

typedef __hip_bfloat16 bf16;
typedef _Float16 fp16;
typedef __attribute__((ext_vector_type(8)))  short  short8;
typedef __attribute__((ext_vector_type(16))) float  floatx16;

#define HW 65536   // 256*256

__device__ __forceinline__ bf16  f2b(float v){ return __float2bfloat16(v); }
__device__ __forceinline__ unsigned short f2bu(float v){
  union { bf16 h; unsigned short u; } cv; cv.h = __float2bfloat16(v); return cv.u;
}
__device__ __forceinline__ float bu2f(unsigned short u){
  union { unsigned u; float f; } cv; cv.u = ((unsigned)u) << 16; return cv.f;
}
__device__ __forceinline__ unsigned short f2hu(float v){
  union { fp16 h; unsigned short u; } cv; cv.h = (fp16)v; return cv.u;
}
__device__ __forceinline__ float hu2f(unsigned short u){
  union { fp16 h; unsigned short u; } cv; cv.u = u; return (float)cv.h;
}

// ---- fused: maxpool+1x1-in (blocks 0..2047) | weight prep + lang (2048..2343) ----
// wb granule oc-permutation: column (nt,c31) holds actual oc = 2*c31 + nt, so a
// conv lane (l31) computes ADJACENT channels {2*l31, 2*l31+1} -> packed u32 stores.
__global__ __launch_bounds__(256) void setup_pool_kernel(
    const float* __restrict__ sm, const float* __restrict__ w_in,
    const float* __restrict__ b_in, fp16* __restrict__ x, bf16* __restrict__ h1,
    const float* __restrict__ w_d3, const float* __restrict__ w_d1,
    bf16* __restrict__ wb3, bf16* __restrict__ wb1,
    const float* __restrict__ action,
    const float* __restrict__ w_a1, const float* __restrict__ b_a1,
    const float* __restrict__ w_a2, const float* __restrict__ b_a2,
    float* __restrict__ lang){
  int blk = blockIdx.x;
  if (blk < 2048){
    int p = blk*256 + threadIdx.x;
    int n = p >> 16; int ij = p & 65535; int i = ij >> 8; int j = ij & 255;
    const float* smn = sm + ((long)n << 23);   // n*32*512*512
    float xv[32];
    #pragma unroll
    for (int d = 0; d < 32; d++){
      long base = ((long)(d*512 + 2*i) << 9) + 2*j;
      float2 p0 = *reinterpret_cast<const float2*>(smn + base);
      float2 p1 = *reinterpret_cast<const float2*>(smn + base + 512);
      xv[d] = fmaxf(fmaxf(p0.x, p0.y), fmaxf(p1.x, p1.y));
    }
    unsigned xw[16];
    #pragma unroll
    for (int q = 0; q < 16; q++)
      xw[q] = ((unsigned)f2hu(xv[2*q+1]) << 16) | f2hu(xv[2*q]);
    uint4* xo = reinterpret_cast<uint4*>((char*)x + ((long)p << 6));  // 64 B/pixel
    #pragma unroll
    for (int q = 0; q < 4; q++)
      xo[q] = make_uint4(xw[4*q], xw[4*q+1], xw[4*q+2], xw[4*q+3]);
    unsigned ow[32];
    #pragma unroll 4
    for (int c = 0; c < 64; c += 2){
      float a0 = b_in[c], a1 = b_in[c+1];
      #pragma unroll
      for (int d = 0; d < 32; d++){
        a0 += xv[d]*w_in[c*32+d];
        a1 += xv[d]*w_in[(c+1)*32+d];
      }
      ow[c>>1] = ((unsigned)f2bu(fmaxf(a1,0.f)) << 16) | f2bu(fmaxf(a0,0.f));
    }
    uint4* ho = reinterpret_cast<uint4*>((char*)h1 + ((long)p << 7));
    #pragma unroll
    for (int q = 0; q < 8; q++)
      ho[q] = make_uint4(ow[4*q], ow[4*q+1], ow[4*q+2], ow[4*q+3]);
  } else {
    int b = blk - 2048;
    if (b < 288){
      const float* w = (b < 144) ? w_d3 : w_d1;
      bf16* wb = (b < 144) ? wb3 : wb1;
      int i = (b < 144 ? b : b - 144)*256 + threadIdx.x;
      if (i >= 36864) return;
      int j    = i & 7;
      int gran = i >> 3;
      int col  = gran & 63;
      int oc   = ((col & 31) << 1) | (col >> 5);   // permuted: lane l31 -> oc {2*l31, 2*l31+1}
      int rest = gran >> 6;          // (t*4+ks)*2+half
      int half = rest & 1;
      int ks   = (rest >> 1) & 3;
      int t    = rest >> 3;
      int e  = ks*16 + half*8 + j;
      int ki = t / 3, kj = t - ki*3;
      wb[i] = f2b(w[(oc*64 + e)*9 + ki*3 + kj]);
    } else {
      int n = b - 288;
      int t = threadIdx.x;
      __shared__ float part[256];
      __shared__ float hid[64];
      int d = t & 63, q = t >> 6;
      const float* ar = action + n*256;
      float a = 0.f;
      #pragma unroll 8
      for (int i = q*64; i < q*64 + 64; i++) a += ar[i]*w_a1[i*64 + d];
      part[t] = a;
      __syncthreads();
      if (t < 64)
        hid[t] = fmaxf(b_a1[t] + part[t] + part[64+t] + part[128+t] + part[192+t], 0.f);
      __syncthreads();
      if (t < 49){
        float l = b_a2[t];
        #pragma unroll 8
        for (int j2 = 0; j2 < 64; j2++) l += hid[j2]*w_a2[j2*49 + t];
        lang[n*49 + t] = l;    // unnormalized: per-n LSE cancels in final log_softmax
      }
    }
  }
}

// ---- 3x3 dil=3 conv 64->64 + relu via MFMA implicit GEMM; NHWC in/out ----
// Permuted columns: lane l31 owns oc {2*l31, 2*l31+1} -> one packed u32 store per reg.
template<int DIL>
__global__ __launch_bounds__(256) void conv3x3_mfma(
    const bf16* __restrict__ hin, const bf16* __restrict__ wb,
    const float* __restrict__ bias, bf16* __restrict__ hout){
  constexpr int R = 16 + 2*DIL, C = 16 + 2*DIL, NPIX = R*C;
  __shared__ __align__(16) char tile[NPIX*128];   // [pix][64e] bf16, XOR-swizzled granules
  int b = blockIdx.x;
  int n = b & 7; int tb = b >> 3;                 // XCD-aware: image n pinned to XCD
  int i0 = (tb >> 4) << 4, j0 = (tb & 15) << 4;
  int tid = threadIdx.x;
  const bf16* hn = hin + ((long)n << 22);  // n*HW*64
  for (int s = tid; s < NPIX*8; s += 256){
    int pix = s >> 3, g = s & 7;
    int r = pix / C, c = pix - r*C;
    int gi = i0 - DIL + r, gj = j0 - DIL + c;
    uint4 v = make_uint4(0u,0u,0u,0u);
    if (gi >= 0 && gi < 256 && gj >= 0 && gj < 256)
      v = *reinterpret_cast<const uint4*>(hn + (((long)((gi<<8) + gj)) << 6) + (g<<3));
    *reinterpret_cast<uint4*>(tile + pix*128 + ((g ^ (pix & 7)) << 4)) = v;
  }
  __syncthreads();
  int lane = tid & 63, wv = tid >> 6;
  int l31 = lane & 31, half = lane >> 5;
  floatx16 acc[2][2];
  #pragma unroll
  for (int m2 = 0; m2 < 2; m2++){
    acc[m2][0] = (floatx16)(0.0f);
    acc[m2][1] = (floatx16)(0.0f);
  }
  int prr[2], pcc[2];
  #pragma unroll
  for (int m2 = 0; m2 < 2; m2++){
    int pidx = (wv*2 + m2)*32 + l31;
    prr[m2] = pidx >> 4; pcc[m2] = pidx & 15;
  }
  const char* wbc = reinterpret_cast<const char*>(wb);
  for (int t = 0; t < 9; t++){
    int ki = t / 3, kj = t - ki*3;
    int pp[2];
    #pragma unroll
    for (int m2 = 0; m2 < 2; m2++)
      pp[m2] = (prr[m2] + ki*DIL)*C + (pcc[m2] + kj*DIL);
    short8 bfr[4][2];
    #pragma unroll
    for (int ks = 0; ks < 4; ks++){
      #pragma unroll
      for (int nt = 0; nt < 2; nt++)
        bfr[ks][nt] = *reinterpret_cast<const short8*>(
            wbc + ((((t*4 + ks)*2 + half)*64 + nt*32 + l31) << 4));
    }
    #pragma unroll
    for (int ks = 0; ks < 4; ks++){
      #pragma unroll
      for (int m2 = 0; m2 < 2; m2++){
        short8 afrag = *reinterpret_cast<const short8*>(
            tile + pp[m2]*128 + (((ks*2 + half) ^ (pp[m2] & 7)) << 4));
        acc[m2][0] = __builtin_amdgcn_mfma_f32_32x32x16_bf16(afrag, bfr[ks][0], acc[m2][0], 0, 0, 0);
        acc[m2][1] = __builtin_amdgcn_mfma_f32_32x32x16_bf16(afrag, bfr[ks][1], acc[m2][1], 0, 0, 0);
      }
    }
  }
  float bv0 = bias[2*l31], bv1 = bias[2*l31+1];
  bf16* ho = hout + ((long)n << 22);
  #pragma unroll
  for (int m2 = 0; m2 < 2; m2++){
    #pragma unroll
    for (int reg = 0; reg < 16; reg++){
      int row = (reg & 3) + 8*(reg >> 2) + 4*half;     // C/D layout, 32x32 [m74/m101]
      int pidx = (wv*2 + m2)*32 + row;
      int pr = pidx >> 4, pc = pidx & 15;
      int off = ((i0+pr)<<8) + (j0+pc);
      unsigned pk = ((unsigned)f2bu(fmaxf(acc[m2][1][reg] + bv1, 0.f)) << 16)
                  |  f2bu(fmaxf(acc[m2][0][reg] + bv0, 0.f));
      *reinterpret_cast<unsigned*>((char*)ho + (((long)off) << 7) + (l31 << 2)) = pk;
    }
  }
}

// ---- fused: 3x3 dil=1 conv 64->64 + relu (MFMA) -> LDS -> per-pixel
//      residual 1x1 64->32, 1x1 32->49 + lang, log_softmax; lk fp16 NCHW out ----
__global__ __launch_bounds__(256) void conv1_out_kernel(
    const bf16* __restrict__ hin, const bf16* __restrict__ wb,
    const float* __restrict__ bias, const fp16* __restrict__ x,
    const float* __restrict__ w_out, const float* __restrict__ b_out,
    const float* __restrict__ w_k, const float* __restrict__ b_k,
    const float* __restrict__ lang, fp16* __restrict__ lk){
  constexpr int DIL = 1, R = 18, C = 18, NPIX = R*C;
  __shared__ __align__(16) char tile[NPIX*128];   // 41472 B; reused for conv output
  int b = blockIdx.x;
  int n = b & 7; int tb = b >> 3;
  int i0 = (tb >> 4) << 4, j0 = (tb & 15) << 4;
  int tid = threadIdx.x;
  const bf16* hn = hin + ((long)n << 22);
  for (int s = tid; s < NPIX*8; s += 256){
    int pix = s >> 3, g = s & 7;
    int r = pix / C, c = pix - r*C;
    int gi = i0 - DIL + r, gj = j0 - DIL + c;
    uint4 v = make_uint4(0u,0u,0u,0u);
    if (gi >= 0 && gi < 256 && gj >= 0 && gj < 256)
      v = *reinterpret_cast<const uint4*>(hn + (((long)((gi<<8) + gj)) << 6) + (g<<3));
    *reinterpret_cast<uint4*>(tile + pix*128 + ((g ^ (pix & 7)) << 4)) = v;
  }
  __syncthreads();
  int lane = tid & 63, wv = tid >> 6;
  int l31 = lane & 31, half = lane >> 5;
  floatx16 acc[2][2];
  #pragma unroll
  for (int m2 = 0; m2 < 2; m2++){
    acc[m2][0] = (floatx16)(0.0f);
    acc[m2][1] = (floatx16)(0.0f);
  }
  int prr[2], pcc[2];
  #pragma unroll
  for (int m2 = 0; m2 < 2; m2++){
    int pidx = (wv*2 + m2)*32 + l31;
    prr[m2] = pidx >> 4; pcc[m2] = pidx & 15;
  }
  const char* wbc = reinterpret_cast<const char*>(wb);
  for (int t = 0; t < 9; t++){
    int ki = t / 3, kj = t - ki*3;
    int pp[2];
    #pragma unroll
    for (int m2 = 0; m2 < 2; m2++)
      pp[m2] = (prr[m2] + ki)*C + (pcc[m2] + kj);
    short8 bfr[4][2];
    #pragma unroll
    for (int ks = 0; ks < 4; ks++){
      #pragma unroll
      for (int nt = 0; nt < 2; nt++)
        bfr[ks][nt] = *reinterpret_cast<const short8*>(
            wbc + ((((t*4 + ks)*2 + half)*64 + nt*32 + l31) << 4));
    }
    #pragma unroll
    for (int ks = 0; ks < 4; ks++){
      #pragma unroll
      for (int m2 = 0; m2 < 2; m2++){
        short8 afrag = *reinterpret_cast<const short8*>(
            tile + pp[m2]*128 + (((ks*2 + half) ^ (pp[m2] & 7)) << 4));
        acc[m2][0] = __builtin_amdgcn_mfma_f32_32x32x16_bf16(afrag, bfr[ks][0], acc[m2][0], 0, 0, 0);
        acc[m2][1] = __builtin_amdgcn_mfma_f32_32x32x16_bf16(afrag, bfr[ks][1], acc[m2][1], 0, 0, 0);
      }
    }
  }
  __syncthreads();   // all waves done reading staged tile before overwrite
  // epilogue -> LDS: channel pair (2*l31, 2*l31+1) packed u32, swizzled granules
  float bv0 = bias[2*l31], bv1 = bias[2*l31+1];
  #pragma unroll
  for (int m2 = 0; m2 < 2; m2++){
    #pragma unroll
    for (int reg = 0; reg < 16; reg++){
      int row = (reg & 3) + 8*(reg >> 2) + 4*half;
      int pidx = (wv*2 + m2)*32 + row;
      unsigned pk = ((unsigned)f2bu(fmaxf(acc[m2][1][reg] + bv1, 0.f)) << 16)
                  |  f2bu(fmaxf(acc[m2][0][reg] + bv0, 0.f));
      // channel c=2*l31: granule g=l31>>2 (xor pix&7), in-granule byte (l31&3)*4
      *reinterpret_cast<unsigned*>(
          tile + pidx*128 + ((((l31>>2) ^ (pidx & 7))) << 4) + ((l31 & 3) << 2)) = pk;
    }
  }
  __syncthreads();
  // per-pixel out_motion: thread t owns tile pixel t
  int pr = tid >> 4, pc = tid & 15;
  int ij = ((i0 + pr) << 8) | (j0 + pc);
  long p = ((long)n << 16) | ij;
  float o[32];
  { const uint4* xp = reinterpret_cast<const uint4*>((const char*)x + (p << 6));
    #pragma unroll
    for (int q = 0; q < 4; q++){
      uint4 u = xp[q];
      unsigned uu[4] = {u.x, u.y, u.z, u.w};
      #pragma unroll
      for (int k = 0; k < 4; k++){
        o[q*8 + 2*k]   = hu2f((unsigned short)(uu[k] & 0xffffu));
        o[q*8 + 2*k+1] = hu2f((unsigned short)(uu[k] >> 16));
      }
    }
  }
  #pragma unroll
  for (int d = 0; d < 32; d++) o[d] += b_out[d];
  #pragma unroll
  for (int q = 0; q < 8; q++){
    uint4 u = *reinterpret_cast<const uint4*>(tile + tid*128 + ((q ^ (tid & 7)) << 4));
    unsigned uu[4] = {u.x, u.y, u.z, u.w};
    float hvv[8];
    #pragma unroll
    for (int k = 0; k < 4; k++){
      hvv[2*k]   = bu2f((unsigned short)(uu[k] & 0xffffu));
      hvv[2*k+1] = bu2f((unsigned short)(uu[k] >> 16));
    }
    #pragma unroll
    for (int d = 0; d < 32; d++){
      float s = 0.f;
      #pragma unroll
      for (int cc = 0; cc < 8; cc++) s += hvv[cc]*w_out[d*64 + q*8 + cc];
      o[d] += s;
    }
  }
  float lg[49]; float m = -1e30f;
  #pragma unroll 7
  for (int k = 0; k < 49; k++){
    float acc2 = b_k[k] + lang[n*49+k];
    #pragma unroll
    for (int d = 0; d < 32; d++) acc2 += o[d]*w_k[k*32+d];
    lg[k] = acc2; m = fmaxf(m, acc2);
  }
  float s = 0.f;
  #pragma unroll
  for (int k = 0; k < 49; k++) s += __expf(lg[k]-m);
  float lse = m + __logf(s);
  #pragma unroll
  for (int k = 0; k < 49; k++)
    lk[(long)n*49*HW + (long)k*HW + ij] = (fp16)(lg[k] - lse);
}

// ---- 7x7 gather logsumexp (f32 output); lk fp16, XCD-swizzled rows ----
__global__ __launch_bounds__(256) void gather_lse_kernel(
    const float* __restrict__ lb, const fp16* __restrict__ lk, float* __restrict__ out){
  int b = blockIdx.x;
  int n = b & 7;                         // XCD-aware: image n pinned to XCD
  int ij = ((b >> 3) << 8) | threadIdx.x;
  int i = ij >> 8; int j = ij & 255;
  const fp16* lkn = lk + (long)n*49*HW;
  float v[49]; float m = -1e30f;
  #pragma unroll
  for (int ki = 0; ki < 7; ki++){
    int h = i + 3 - ki;
    bool hok = (h >= 0 && h < 256);
    #pragma unroll
    for (int kj = 0; kj < 7; kj++){
      int w = j + 3 - kj;
      float val = -1e30f;
      if (hok && w >= 0 && w < 256){
        int q = h*256 + w;
        val = lb[n*HW + q] + (float)lkn[(ki*7+kj)*HW + q];
      }
      v[ki*7+kj] = val; m = fmaxf(m, val);
    }
  }
  float s = 0.f;
  #pragma unroll
  for (int t = 0; t < 49; t++) s += __expf(v[t]-m);
  out[n*HW + ij] = m + __logf(s);
}

// ---- launch ----
// ws layout (bytes):
//   x    fp16 NHWC [8][65536][32] @ 0           (33,554,432)
//   h1   bf16 NHWC [8][65536][64] @  67,108,864 (67,108,864)  dead after conv<3>
//   lk   fp16 [8][49][65536]     @  67,108,864  (51,380,224)  overlaps dead h1
//   h2   bf16 NHWC               @ 134,217,728  (67,108,864)
//   lang f32  [8][49]            @ 236,978,176  (1,792)
//   wb3  bf16 granules           @ 236,979,968  (73,728)
//   wb1  bf16 granules           @ 237,053,696  (73,728)
extern "C" void kernel_launch(void* const* d_in, const int* in_sizes, int n_in,
                              void* d_out, int out_size, void* d_ws, size_t ws_size,
                              hipStream_t stream) {
  (void)in_sizes; (void)n_in; (void)out_size; (void)ws_size;
  const float* lb    = (const float*)d_in[0];
  const float* sm    = (const float*)d_in[1];
  const float* act   = (const float*)d_in[2];
  const float* w_in  = (const float*)d_in[3];
  const float* b_in  = (const float*)d_in[4];
  const float* w_d3  = (const float*)d_in[5];
  const float* b_d3  = (const float*)d_in[6];
  const float* w_d1  = (const float*)d_in[7];
  const float* b_d1  = (const float*)d_in[8];
  const float* w_out = (const float*)d_in[9];
  const float* b_out = (const float*)d_in[10];
  const float* w_k   = (const float*)d_in[11];
  const float* b_k   = (const float*)d_in[12];
  const float* w_a1  = (const float*)d_in[13];
  const float* b_a1  = (const float*)d_in[14];
  const float* w_a2  = (const float*)d_in[15];
  const float* b_a2  = (const float*)d_in[16];
  float* out = (float*)d_out;

  char* ws = (char*)d_ws;
  fp16*  x    = (fp16*) (ws + 0);
  bf16*  h1   = (bf16*) (ws + 67108864);
  fp16*  lk   = (fp16*) (ws + 67108864);
  bf16*  h2   = (bf16*) (ws + 134217728);
  float* lang = (float*)(ws + 236978176);
  bf16*  wb3  = (bf16*) (ws + 236979968);
  bf16*  wb1  = (bf16*) (ws + 237053696);

  setup_pool_kernel<<<2344, 256, 0, stream>>>(sm, w_in, b_in, x, h1,
                                              w_d3, w_d1, wb3, wb1,
                                              act, w_a1, b_a1, w_a2, b_a2, lang);
  conv3x3_mfma<3><<<2048, 256, 0, stream>>>(h1, wb3, b_d3, h2);
  conv1_out_kernel<<<2048, 256, 0, stream>>>(h2, wb1, b_d1, x, w_out, b_out,
                                             w_k, b_k, lang, lk);
  gather_lse_kernel<<<2048, 256, 0, stream>>>(lb, lk, out);
}

// Round 4
// 662.033 us; speedup vs baseline: 1.0854x; 1.0239x over previous
//
#include <hip/hip_runtime.h>
#include <hip/hip_bf16.h>

typedef __hip_bfloat16 bf16;
typedef _Float16 fp16;
typedef __attribute__((ext_vector_type(8)))  short  short8;
typedef __attribute__((ext_vector_type(16))) float  floatx16;

#define HW 65536   // 256*256

__device__ __forceinline__ bf16  f2b(float v){ return __float2bfloat16(v); }
__device__ __forceinline__ unsigned short f2bu(float v){
  union { bf16 h; unsigned short u; } cv; cv.h = __float2bfloat16(v); return cv.u;
}
__device__ __forceinline__ float bu2f(unsigned short u){
  union { unsigned u; float f; } cv; cv.u = ((unsigned)u) << 16; return cv.f;
}
__device__ __forceinline__ unsigned short f2hu(float v){
  union { fp16 h; unsigned short u; } cv; cv.h = (fp16)v; return cv.u;
}
__device__ __forceinline__ float hu2f(unsigned short u){
  union { fp16 h; unsigned short u; } cv; cv.u = u; return (float)cv.h;
}

// ---- fused: maxpool+1x1-in (blocks 0..2047) | weight prep + lang (2048..2343) ----
// wb granule oc-permutation: column (nt,c31) holds actual oc = 2*c31 + nt, so a
// conv lane (l31) computes ADJACENT channels {2*l31, 2*l31+1} -> packed u32 stores.
__global__ __launch_bounds__(256) void setup_pool_kernel(
    const float* __restrict__ sm, const float* __restrict__ w_in,
    const float* __restrict__ b_in, fp16* __restrict__ x, bf16* __restrict__ h1,
    const float* __restrict__ w_d3, const float* __restrict__ w_d1,
    bf16* __restrict__ wb3, bf16* __restrict__ wb1,
    const float* __restrict__ action,
    const float* __restrict__ w_a1, const float* __restrict__ b_a1,
    const float* __restrict__ w_a2, const float* __restrict__ b_a2,
    float* __restrict__ lang){
  int blk = blockIdx.x;
  if (blk < 2048){
    int p = blk*256 + threadIdx.x;
    int n = p >> 16; int ij = p & 65535; int i = ij >> 8; int j = ij & 255;
    const float* smn = sm + ((long)n << 23);   // n*32*512*512
    float xv[32];
    #pragma unroll
    for (int d = 0; d < 32; d++){
      long base = ((long)(d*512 + 2*i) << 9) + 2*j;
      float2 p0 = *reinterpret_cast<const float2*>(smn + base);
      float2 p1 = *reinterpret_cast<const float2*>(smn + base + 512);
      xv[d] = fmaxf(fmaxf(p0.x, p0.y), fmaxf(p1.x, p1.y));
    }
    unsigned xw[16];
    #pragma unroll
    for (int q = 0; q < 16; q++)
      xw[q] = ((unsigned)f2hu(xv[2*q+1]) << 16) | f2hu(xv[2*q]);
    uint4* xo = reinterpret_cast<uint4*>((char*)x + ((long)p << 6));  // 64 B/pixel
    #pragma unroll
    for (int q = 0; q < 4; q++)
      xo[q] = make_uint4(xw[4*q], xw[4*q+1], xw[4*q+2], xw[4*q+3]);
    unsigned ow[32];
    #pragma unroll 4
    for (int c = 0; c < 64; c += 2){
      float a0 = b_in[c], a1 = b_in[c+1];
      #pragma unroll
      for (int d = 0; d < 32; d++){
        a0 += xv[d]*w_in[c*32+d];
        a1 += xv[d]*w_in[(c+1)*32+d];
      }
      ow[c>>1] = ((unsigned)f2bu(fmaxf(a1,0.f)) << 16) | f2bu(fmaxf(a0,0.f));
    }
    uint4* ho = reinterpret_cast<uint4*>((char*)h1 + ((long)p << 7));
    #pragma unroll
    for (int q = 0; q < 8; q++)
      ho[q] = make_uint4(ow[4*q], ow[4*q+1], ow[4*q+2], ow[4*q+3]);
  } else {
    int b = blk - 2048;
    if (b < 288){
      const float* w = (b < 144) ? w_d3 : w_d1;
      bf16* wb = (b < 144) ? wb3 : wb1;
      int i = (b < 144 ? b : b - 144)*256 + threadIdx.x;
      if (i >= 36864) return;
      int j    = i & 7;
      int gran = i >> 3;
      int col  = gran & 63;
      int oc   = ((col & 31) << 1) | (col >> 5);   // permuted: lane l31 -> oc {2*l31, 2*l31+1}
      int rest = gran >> 6;          // (t*4+ks)*2+half
      int half = rest & 1;
      int ks   = (rest >> 1) & 3;
      int t    = rest >> 3;
      int e  = ks*16 + half*8 + j;
      int ki = t / 3, kj = t - ki*3;
      wb[i] = f2b(w[(oc*64 + e)*9 + ki*3 + kj]);
    } else {
      int n = b - 288;
      int t = threadIdx.x;
      __shared__ float part[256];
      __shared__ float hid[64];
      int d = t & 63, q = t >> 6;
      const float* ar = action + n*256;
      float a = 0.f;
      #pragma unroll 8
      for (int i = q*64; i < q*64 + 64; i++) a += ar[i]*w_a1[i*64 + d];
      part[t] = a;
      __syncthreads();
      if (t < 64)
        hid[t] = fmaxf(b_a1[t] + part[t] + part[64+t] + part[128+t] + part[192+t], 0.f);
      __syncthreads();
      if (t < 49){
        float l = b_a2[t];
        #pragma unroll 8
        for (int j2 = 0; j2 < 64; j2++) l += hid[j2]*w_a2[j2*49 + t];
        lang[n*49 + t] = l;    // unnormalized: per-n LSE cancels in final log_softmax
      }
    }
  }
}

// ---- 3x3 conv 64->64 + relu via MFMA implicit GEMM; NHWC in/out ----
// block = 256 thr (4 waves), 16x16 spatial tile, M=256 pix, N=64 oc, K=576.
// Each wave owns m-tile pair {wv*2, wv*2+1} and BOTH n-tiles (all 64 oc).
// Permuted columns: lane l31 owns oc {2*l31, 2*l31+1} -> one packed u32 store/reg.
// XCD swizzle: n = b&7 pins each image to one XCD's L2 for halo reuse.
template<int DIL>
__global__ __launch_bounds__(256) void conv3x3_mfma(
    const bf16* __restrict__ hin, const bf16* __restrict__ wb,
    const float* __restrict__ bias, bf16* __restrict__ hout){
  constexpr int R = 16 + 2*DIL, C = 16 + 2*DIL, NPIX = R*C;
  __shared__ __align__(16) char tile[NPIX*128];   // [pix][64e] bf16, XOR-swizzled granules
  int b = blockIdx.x;
  int n = b & 7; int tb = b >> 3;
  int i0 = (tb >> 4) << 4, j0 = (tb & 15) << 4;
  int tid = threadIdx.x;
  const bf16* hn = hin + ((long)n << 22);  // n*HW*64
  for (int s = tid; s < NPIX*8; s += 256){
    int pix = s >> 3, g = s & 7;
    int r = pix / C, c = pix - r*C;
    int gi = i0 - DIL + r, gj = j0 - DIL + c;
    uint4 v = make_uint4(0u,0u,0u,0u);
    if (gi >= 0 && gi < 256 && gj >= 0 && gj < 256)
      v = *reinterpret_cast<const uint4*>(hn + (((long)((gi<<8) + gj)) << 6) + (g<<3));
    *reinterpret_cast<uint4*>(tile + pix*128 + ((g ^ (pix & 7)) << 4)) = v;
  }
  __syncthreads();
  int lane = tid & 63, wv = tid >> 6;
  int l31 = lane & 31, half = lane >> 5;
  floatx16 acc[2][2];
  #pragma unroll
  for (int m2 = 0; m2 < 2; m2++){
    acc[m2][0] = (floatx16)(0.0f);
    acc[m2][1] = (floatx16)(0.0f);
  }
  int prr[2], pcc[2];
  #pragma unroll
  for (int m2 = 0; m2 < 2; m2++){
    int pidx = (wv*2 + m2)*32 + l31;
    prr[m2] = pidx >> 4; pcc[m2] = pidx & 15;
  }
  const char* wbc = reinterpret_cast<const char*>(wb);
  for (int t = 0; t < 9; t++){
    int ki = t / 3, kj = t - ki*3;
    int pp[2];
    #pragma unroll
    for (int m2 = 0; m2 < 2; m2++)
      pp[m2] = (prr[m2] + ki*DIL)*C + (pcc[m2] + kj*DIL);
    short8 bfr[4][2];
    #pragma unroll
    for (int ks = 0; ks < 4; ks++){
      #pragma unroll
      for (int nt = 0; nt < 2; nt++)
        bfr[ks][nt] = *reinterpret_cast<const short8*>(
            wbc + ((((t*4 + ks)*2 + half)*64 + nt*32 + l31) << 4));
    }
    #pragma unroll
    for (int ks = 0; ks < 4; ks++){
      #pragma unroll
      for (int m2 = 0; m2 < 2; m2++){
        short8 afrag = *reinterpret_cast<const short8*>(
            tile + pp[m2]*128 + (((ks*2 + half) ^ (pp[m2] & 7)) << 4));
        acc[m2][0] = __builtin_amdgcn_mfma_f32_32x32x16_bf16(afrag, bfr[ks][0], acc[m2][0], 0, 0, 0);
        acc[m2][1] = __builtin_amdgcn_mfma_f32_32x32x16_bf16(afrag, bfr[ks][1], acc[m2][1], 0, 0, 0);
      }
    }
  }
  float bv0 = bias[2*l31], bv1 = bias[2*l31+1];
  bf16* ho = hout + ((long)n << 22);
  #pragma unroll
  for (int m2 = 0; m2 < 2; m2++){
    #pragma unroll
    for (int reg = 0; reg < 16; reg++){
      int row = (reg & 3) + 8*(reg >> 2) + 4*half;     // C/D layout, 32x32 [m74/m101]
      int pidx = (wv*2 + m2)*32 + row;
      int pr = pidx >> 4, pc = pidx & 15;
      int off = ((i0+pr)<<8) + (j0+pc);
      unsigned pk = ((unsigned)f2bu(fmaxf(acc[m2][1][reg] + bv1, 0.f)) << 16)
                  |  f2bu(fmaxf(acc[m2][0][reg] + bv0, 0.f));
      *reinterpret_cast<unsigned*>((char*)ho + (((long)off) << 7) + (l31 << 2)) = pk;
    }
  }
}

// ---- residual 1x1 64->32, 1x1 32->49 + lang, fused log_softmax; NHWC in, lk fp16 NCHW out
// Row-major blocks: wave writes 128 B contiguous per k-plane (full coalescing).
__global__ __launch_bounds__(256) void out_motion_kernel(
    const bf16* __restrict__ h3, const fp16* __restrict__ x,
    const float* __restrict__ w_out, const float* __restrict__ b_out,
    const float* __restrict__ w_k, const float* __restrict__ b_k,
    const float* __restrict__ lang, fp16* __restrict__ lk){
  int p = blockIdx.x*256 + threadIdx.x;
  int n = p >> 16; int ij = p & 65535;
  float hv[64];
  const uint4* hp = reinterpret_cast<const uint4*>((const char*)h3 + ((long)p << 7));
  #pragma unroll
  for (int q = 0; q < 8; q++){
    uint4 u = hp[q];
    unsigned uu[4] = {u.x, u.y, u.z, u.w};
    #pragma unroll
    for (int k = 0; k < 4; k++){
      hv[q*8 + 2*k]   = bu2f((unsigned short)(uu[k] & 0xffffu));
      hv[q*8 + 2*k+1] = bu2f((unsigned short)(uu[k] >> 16));
    }
  }
  float o[32];
  const uint4* xp = reinterpret_cast<const uint4*>((const char*)x + ((long)p << 6));
  #pragma unroll
  for (int q = 0; q < 4; q++){
    uint4 u = xp[q];
    unsigned uu[4] = {u.x, u.y, u.z, u.w};
    #pragma unroll
    for (int k = 0; k < 4; k++){
      o[q*8 + 2*k]   = hu2f((unsigned short)(uu[k] & 0xffffu));
      o[q*8 + 2*k+1] = hu2f((unsigned short)(uu[k] >> 16));
    }
  }
  #pragma unroll 4
  for (int d = 0; d < 32; d++){
    float acc = b_out[d];
    #pragma unroll
    for (int e = 0; e < 64; e++) acc += hv[e]*w_out[d*64+e];
    o[d] += acc;
  }
  float lg[49]; float m = -1e30f;
  #pragma unroll 7
  for (int k = 0; k < 49; k++){
    float acc = b_k[k] + lang[n*49+k];
    #pragma unroll
    for (int d = 0; d < 32; d++) acc += o[d]*w_k[k*32+d];
    lg[k] = acc; m = fmaxf(m, acc);
  }
  float s = 0.f;
  #pragma unroll
  for (int k = 0; k < 49; k++) s += __expf(lg[k]-m);
  float lse = m + __logf(s);
  #pragma unroll
  for (int k = 0; k < 49; k++)
    lk[(long)n*49*HW + (long)k*HW + ij] = (fp16)(lg[k] - lse);
}

// ---- 7x7 gather logsumexp (f32 output); lk fp16, XCD-swizzled rows ----
__global__ __launch_bounds__(256) void gather_lse_kernel(
    const float* __restrict__ lb, const fp16* __restrict__ lk, float* __restrict__ out){
  int b = blockIdx.x;
  int n = b & 7;                         // XCD-aware: image n pinned to XCD
  int ij = ((b >> 3) << 8) | threadIdx.x;
  int i = ij >> 8; int j = ij & 255;
  const fp16* lkn = lk + (long)n*49*HW;
  float v[49]; float m = -1e30f;
  #pragma unroll
  for (int ki = 0; ki < 7; ki++){
    int h = i + 3 - ki;
    bool hok = (h >= 0 && h < 256);
    #pragma unroll
    for (int kj = 0; kj < 7; kj++){
      int w = j + 3 - kj;
      float val = -1e30f;
      if (hok && w >= 0 && w < 256){
        int q = h*256 + w;
        val = lb[n*HW + q] + (float)lkn[(ki*7+kj)*HW + q];
      }
      v[ki*7+kj] = val; m = fmaxf(m, val);
    }
  }
  float s = 0.f;
  #pragma unroll
  for (int t = 0; t < 49; t++) s += __expf(v[t]-m);
  out[n*HW + ij] = m + __logf(s);
}

// ---- launch ----
// ws layout (bytes):
//   x    fp16 NHWC [8][65536][32] @ 0           (33,554,432)
//   h1   bf16 NHWC [8][65536][64] @  67,108,864 (67,108,864)
//   h2   bf16 NHWC               @ 134,217,728  (67,108,864)  dead after conv<1>
//   lk   fp16 [8][49][65536]     @ 134,217,728  (51,380,224)  overlaps dead h2
//   lang f32  [8][49]            @ 236,978,176  (1,792)
//   wb3  bf16 granules           @ 236,979,968  (73,728)
//   wb1  bf16 granules           @ 237,053,696  (73,728)
extern "C" void kernel_launch(void* const* d_in, const int* in_sizes, int n_in,
                              void* d_out, int out_size, void* d_ws, size_t ws_size,
                              hipStream_t stream) {
  (void)in_sizes; (void)n_in; (void)out_size; (void)ws_size;
  const float* lb    = (const float*)d_in[0];
  const float* sm    = (const float*)d_in[1];
  const float* act   = (const float*)d_in[2];
  const float* w_in  = (const float*)d_in[3];
  const float* b_in  = (const float*)d_in[4];
  const float* w_d3  = (const float*)d_in[5];
  const float* b_d3  = (const float*)d_in[6];
  const float* w_d1  = (const float*)d_in[7];
  const float* b_d1  = (const float*)d_in[8];
  const float* w_out = (const float*)d_in[9];
  const float* b_out = (const float*)d_in[10];
  const float* w_k   = (const float*)d_in[11];
  const float* b_k   = (const float*)d_in[12];
  const float* w_a1  = (const float*)d_in[13];
  const float* b_a1  = (const float*)d_in[14];
  const float* w_a2  = (const float*)d_in[15];
  const float* b_a2  = (const float*)d_in[16];
  float* out = (float*)d_out;

  char* ws = (char*)d_ws;
  fp16*  x    = (fp16*) (ws + 0);
  bf16*  h1   = (bf16*) (ws + 67108864);
  bf16*  h2   = (bf16*) (ws + 134217728);
  fp16*  lk   = (fp16*) (ws + 134217728);
  float* lang = (float*)(ws + 236978176);
  bf16*  wb3  = (bf16*) (ws + 236979968);
  bf16*  wb1  = (bf16*) (ws + 237053696);

  setup_pool_kernel<<<2344, 256, 0, stream>>>(sm, w_in, b_in, x, h1,
                                              w_d3, w_d1, wb3, wb1,
                                              act, w_a1, b_a1, w_a2, b_a2, lang);
  conv3x3_mfma<3><<<2048, 256, 0, stream>>>(h1, wb3, b_d3, h2);
  conv3x3_mfma<1><<<2048, 256, 0, stream>>>(h2, wb1, b_d1, h1);
  out_motion_kernel<<<2048, 256, 0, stream>>>(h1, x, w_out, b_out,
                                              w_k, b_k, lang, lk);
  gather_lse_kernel<<<2048, 256, 0, stream>>>(lb, lk, out);
}

// Round 5
// 652.522 us; speedup vs baseline: 1.1012x; 1.0146x over previous
//
#include <hip/hip_runtime.h>
#include <hip/hip_bf16.h>

typedef __hip_bfloat16 bf16;
typedef _Float16 fp16;
typedef __attribute__((ext_vector_type(8)))  short  short8;
typedef __attribute__((ext_vector_type(16))) float  floatx16;

#define HW 65536   // 256*256

__device__ __forceinline__ bf16  f2b(float v){ return __float2bfloat16(v); }
__device__ __forceinline__ unsigned short f2bu(float v){
  union { bf16 h; unsigned short u; } cv; cv.h = __float2bfloat16(v); return cv.u;
}
__device__ __forceinline__ float bu2f(unsigned short u){
  union { unsigned u; float f; } cv; cv.u = ((unsigned)u) << 16; return cv.f;
}
__device__ __forceinline__ unsigned short f2hu(float v){
  union { fp16 h; unsigned short u; } cv; cv.h = (fp16)v; return cv.u;
}
__device__ __forceinline__ float hu2f(unsigned short u){
  union { fp16 h; unsigned short u; } cv; cv.u = u; return (float)cv.h;
}

// ---- fused: maxpool+1x1-in (blocks 0..2047) | weight prep + lang (2048..2343) ----
// wb granule oc-permutation: column (nt,c31) holds actual oc = 2*c31 + nt, so a
// conv lane (l31) computes ADJACENT channels {2*l31, 2*l31+1} -> packed u32 stores.
__global__ __launch_bounds__(256) void setup_pool_kernel(
    const float* __restrict__ sm, const float* __restrict__ w_in,
    const float* __restrict__ b_in, fp16* __restrict__ x, bf16* __restrict__ h1,
    const float* __restrict__ w_d3, const float* __restrict__ w_d1,
    bf16* __restrict__ wb3, bf16* __restrict__ wb1,
    const float* __restrict__ action,
    const float* __restrict__ w_a1, const float* __restrict__ b_a1,
    const float* __restrict__ w_a2, const float* __restrict__ b_a2,
    float* __restrict__ lang){
  int blk = blockIdx.x;
  if (blk < 2048){
    int p = blk*256 + threadIdx.x;
    int n = p >> 16; int ij = p & 65535; int i = ij >> 8; int j = ij & 255;
    const float* smn = sm + ((long)n << 23);   // n*32*512*512
    float xv[32];
    #pragma unroll
    for (int d = 0; d < 32; d++){
      long base = ((long)(d*512 + 2*i) << 9) + 2*j;
      float2 p0 = *reinterpret_cast<const float2*>(smn + base);
      float2 p1 = *reinterpret_cast<const float2*>(smn + base + 512);
      xv[d] = fmaxf(fmaxf(p0.x, p0.y), fmaxf(p1.x, p1.y));
    }
    unsigned xw[16];
    #pragma unroll
    for (int q = 0; q < 16; q++)
      xw[q] = ((unsigned)f2hu(xv[2*q+1]) << 16) | f2hu(xv[2*q]);
    uint4* xo = reinterpret_cast<uint4*>((char*)x + ((long)p << 6));  // 64 B/pixel
    #pragma unroll
    for (int q = 0; q < 4; q++)
      xo[q] = make_uint4(xw[4*q], xw[4*q+1], xw[4*q+2], xw[4*q+3]);
    unsigned ow[32];
    #pragma unroll 4
    for (int c = 0; c < 64; c += 2){
      float a0 = b_in[c], a1 = b_in[c+1];
      #pragma unroll
      for (int d = 0; d < 32; d++){
        a0 += xv[d]*w_in[c*32+d];
        a1 += xv[d]*w_in[(c+1)*32+d];
      }
      ow[c>>1] = ((unsigned)f2bu(fmaxf(a1,0.f)) << 16) | f2bu(fmaxf(a0,0.f));
    }
    uint4* ho = reinterpret_cast<uint4*>((char*)h1 + ((long)p << 7));
    #pragma unroll
    for (int q = 0; q < 8; q++)
      ho[q] = make_uint4(ow[4*q], ow[4*q+1], ow[4*q+2], ow[4*q+3]);
  } else {
    int b = blk - 2048;
    if (b < 288){
      const float* w = (b < 144) ? w_d3 : w_d1;
      bf16* wb = (b < 144) ? wb3 : wb1;
      int i = (b < 144 ? b : b - 144)*256 + threadIdx.x;
      if (i >= 36864) return;
      int j    = i & 7;
      int gran = i >> 3;
      int col  = gran & 63;
      int oc   = ((col & 31) << 1) | (col >> 5);   // permuted: lane l31 -> oc {2*l31, 2*l31+1}
      int rest = gran >> 6;          // (t*4+ks)*2+half
      int half = rest & 1;
      int ks   = (rest >> 1) & 3;
      int t    = rest >> 3;
      int e  = ks*16 + half*8 + j;
      int ki = t / 3, kj = t - ki*3;
      wb[i] = f2b(w[(oc*64 + e)*9 + ki*3 + kj]);
    } else {
      int n = b - 288;
      int t = threadIdx.x;
      __shared__ float part[256];
      __shared__ float hid[64];
      int d = t & 63, q = t >> 6;
      const float* ar = action + n*256;
      float a = 0.f;
      #pragma unroll 8
      for (int i = q*64; i < q*64 + 64; i++) a += ar[i]*w_a1[i*64 + d];
      part[t] = a;
      __syncthreads();
      if (t < 64)
        hid[t] = fmaxf(b_a1[t] + part[t] + part[64+t] + part[128+t] + part[192+t], 0.f);
      __syncthreads();
      if (t < 49){
        float l = b_a2[t];
        #pragma unroll 8
        for (int j2 = 0; j2 < 64; j2++) l += hid[j2]*w_a2[j2*49 + t];
        lang[n*49 + t] = l;    // unnormalized: per-n LSE cancels in final log_softmax
      }
    }
  }
}

// ---- 3x3 conv 64->64 + relu via MFMA implicit GEMM; NHWC in/out ----
// v3: 512 thr (8 waves), 16x16 spatial tile; wave wv owns ONE m-tile (32 px)
// and BOTH n-tiles -> acc = 32 VGPR/wave, 4 waves/SIMD occupancy (2 blocks/CU).
// Permuted columns: lane l31 owns oc {2*l31, 2*l31+1} -> one packed u32 store/reg.
// XCD swizzle: n = b&7 pins each image to one XCD's L2 for halo reuse.
template<int DIL>
__global__ __launch_bounds__(512, 4) void conv3x3_mfma(
    const bf16* __restrict__ hin, const bf16* __restrict__ wb,
    const float* __restrict__ bias, bf16* __restrict__ hout){
  constexpr int R = 16 + 2*DIL, C = 16 + 2*DIL, NPIX = R*C;
  __shared__ __align__(16) char tile[NPIX*128];   // [pix][64e] bf16, XOR-swizzled granules
  int b = blockIdx.x;
  int n = b & 7; int tb = b >> 3;
  int i0 = (tb >> 4) << 4, j0 = (tb & 15) << 4;
  int tid = threadIdx.x;
  const bf16* hn = hin + ((long)n << 22);  // n*HW*64
  for (int s = tid; s < NPIX*8; s += 512){
    int pix = s >> 3, g = s & 7;
    int r = pix / C, c = pix - r*C;
    int gi = i0 - DIL + r, gj = j0 - DIL + c;
    uint4 v = make_uint4(0u,0u,0u,0u);
    if (gi >= 0 && gi < 256 && gj >= 0 && gj < 256)
      v = *reinterpret_cast<const uint4*>(hn + (((long)((gi<<8) + gj)) << 6) + (g<<3));
    *reinterpret_cast<uint4*>(tile + pix*128 + ((g ^ (pix & 7)) << 4)) = v;
  }
  __syncthreads();
  int lane = tid & 63, wv = tid >> 6;    // wv in [0,8): m-tile index
  int l31 = lane & 31, half = lane >> 5;
  floatx16 acc0 = (floatx16)(0.0f);
  floatx16 acc1 = (floatx16)(0.0f);
  int pidx = wv*32 + l31;
  int prr = pidx >> 4, pcc = pidx & 15;
  const char* wbc = reinterpret_cast<const char*>(wb);
  for (int t = 0; t < 9; t++){
    int ki = t / 3, kj = t - ki*3;
    int pp = (prr + ki*DIL)*C + (pcc + kj*DIL);
    short8 bfr[4][2];
    #pragma unroll
    for (int ks = 0; ks < 4; ks++){
      #pragma unroll
      for (int nt = 0; nt < 2; nt++)
        bfr[ks][nt] = *reinterpret_cast<const short8*>(
            wbc + ((((t*4 + ks)*2 + half)*64 + nt*32 + l31) << 4));
    }
    #pragma unroll
    for (int ks = 0; ks < 4; ks++){
      short8 afrag = *reinterpret_cast<const short8*>(
          tile + pp*128 + (((ks*2 + half) ^ (pp & 7)) << 4));
      acc0 = __builtin_amdgcn_mfma_f32_32x32x16_bf16(afrag, bfr[ks][0], acc0, 0, 0, 0);
      acc1 = __builtin_amdgcn_mfma_f32_32x32x16_bf16(afrag, bfr[ks][1], acc1, 0, 0, 0);
    }
  }
  float bv0 = bias[2*l31], bv1 = bias[2*l31+1];
  bf16* ho = hout + ((long)n << 22);
  #pragma unroll
  for (int reg = 0; reg < 16; reg++){
    int row = (reg & 3) + 8*(reg >> 2) + 4*half;     // C/D layout, 32x32 [m74/m101]
    int po = wv*32 + row;
    int pr = po >> 4, pc = po & 15;
    int off = ((i0+pr)<<8) + (j0+pc);
    unsigned pk = ((unsigned)f2bu(fmaxf(acc1[reg] + bv1, 0.f)) << 16)
                |  f2bu(fmaxf(acc0[reg] + bv0, 0.f));
    *reinterpret_cast<unsigned*>((char*)ho + (((long)off) << 7) + (l31 << 2)) = pk;
  }
}

// ---- residual 1x1 64->32, 1x1 32->49 + lang, fused log_softmax; NHWC in, lk fp16 NCHW out
// Row-major blocks: wave writes 128 B contiguous per k-plane (full coalescing).
__global__ __launch_bounds__(256) void out_motion_kernel(
    const bf16* __restrict__ h3, const fp16* __restrict__ x,
    const float* __restrict__ w_out, const float* __restrict__ b_out,
    const float* __restrict__ w_k, const float* __restrict__ b_k,
    const float* __restrict__ lang, fp16* __restrict__ lk){
  int p = blockIdx.x*256 + threadIdx.x;
  int n = p >> 16; int ij = p & 65535;
  float hv[64];
  const uint4* hp = reinterpret_cast<const uint4*>((const char*)h3 + ((long)p << 7));
  #pragma unroll
  for (int q = 0; q < 8; q++){
    uint4 u = hp[q];
    unsigned uu[4] = {u.x, u.y, u.z, u.w};
    #pragma unroll
    for (int k = 0; k < 4; k++){
      hv[q*8 + 2*k]   = bu2f((unsigned short)(uu[k] & 0xffffu));
      hv[q*8 + 2*k+1] = bu2f((unsigned short)(uu[k] >> 16));
    }
  }
  float o[32];
  const uint4* xp = reinterpret_cast<const uint4*>((const char*)x + ((long)p << 6));
  #pragma unroll
  for (int q = 0; q < 4; q++){
    uint4 u = xp[q];
    unsigned uu[4] = {u.x, u.y, u.z, u.w};
    #pragma unroll
    for (int k = 0; k < 4; k++){
      o[q*8 + 2*k]   = hu2f((unsigned short)(uu[k] & 0xffffu));
      o[q*8 + 2*k+1] = hu2f((unsigned short)(uu[k] >> 16));
    }
  }
  #pragma unroll 4
  for (int d = 0; d < 32; d++){
    float acc = b_out[d];
    #pragma unroll
    for (int e = 0; e < 64; e++) acc += hv[e]*w_out[d*64+e];
    o[d] += acc;
  }
  float lg[49]; float m = -1e30f;
  #pragma unroll 7
  for (int k = 0; k < 49; k++){
    float acc = b_k[k] + lang[n*49+k];
    #pragma unroll
    for (int d = 0; d < 32; d++) acc += o[d]*w_k[k*32+d];
    lg[k] = acc; m = fmaxf(m, acc);
  }
  float s = 0.f;
  #pragma unroll
  for (int k = 0; k < 49; k++) s += __expf(lg[k]-m);
  float lse = m + __logf(s);
  #pragma unroll
  for (int k = 0; k < 49; k++)
    lk[(long)n*49*HW + (long)k*HW + ij] = (fp16)(lg[k] - lse);
}

// ---- 7x7 gather logsumexp (f32 output); lk fp16, XCD-swizzled rows ----
__global__ __launch_bounds__(256) void gather_lse_kernel(
    const float* __restrict__ lb, const fp16* __restrict__ lk, float* __restrict__ out){
  int b = blockIdx.x;
  int n = b & 7;                         // XCD-aware: image n pinned to XCD
  int ij = ((b >> 3) << 8) | threadIdx.x;
  int i = ij >> 8; int j = ij & 255;
  const fp16* lkn = lk + (long)n*49*HW;
  float v[49]; float m = -1e30f;
  #pragma unroll
  for (int ki = 0; ki < 7; ki++){
    int h = i + 3 - ki;
    bool hok = (h >= 0 && h < 256);
    #pragma unroll
    for (int kj = 0; kj < 7; kj++){
      int w = j + 3 - kj;
      float val = -1e30f;
      if (hok && w >= 0 && w < 256){
        int q = h*256 + w;
        val = lb[n*HW + q] + (float)lkn[(ki*7+kj)*HW + q];
      }
      v[ki*7+kj] = val; m = fmaxf(m, val);
    }
  }
  float s = 0.f;
  #pragma unroll
  for (int t = 0; t < 49; t++) s += __expf(v[t]-m);
  out[n*HW + ij] = m + __logf(s);
}

// ---- launch ----
// ws layout (bytes):
//   x    fp16 NHWC [8][65536][32] @ 0           (33,554,432)
//   h1   bf16 NHWC [8][65536][64] @  67,108,864 (67,108,864)
//   h2   bf16 NHWC               @ 134,217,728  (67,108,864)  dead after conv<1>
//   lk   fp16 [8][49][65536]     @ 134,217,728  (51,380,224)  overlaps dead h2
//   lang f32  [8][49]            @ 236,978,176  (1,792)
//   wb3  bf16 granules           @ 236,979,968  (73,728)
//   wb1  bf16 granules           @ 237,053,696  (73,728)
extern "C" void kernel_launch(void* const* d_in, const int* in_sizes, int n_in,
                              void* d_out, int out_size, void* d_ws, size_t ws_size,
                              hipStream_t stream) {
  (void)in_sizes; (void)n_in; (void)out_size; (void)ws_size;
  const float* lb    = (const float*)d_in[0];
  const float* sm    = (const float*)d_in[1];
  const float* act   = (const float*)d_in[2];
  const float* w_in  = (const float*)d_in[3];
  const float* b_in  = (const float*)d_in[4];
  const float* w_d3  = (const float*)d_in[5];
  const float* b_d3  = (const float*)d_in[6];
  const float* w_d1  = (const float*)d_in[7];
  const float* b_d1  = (const float*)d_in[8];
  const float* w_out = (const float*)d_in[9];
  const float* b_out = (const float*)d_in[10];
  const float* w_k   = (const float*)d_in[11];
  const float* b_k   = (const float*)d_in[12];
  const float* w_a1  = (const float*)d_in[13];
  const float* b_a1  = (const float*)d_in[14];
  const float* w_a2  = (const float*)d_in[15];
  const float* b_a2  = (const float*)d_in[16];
  float* out = (float*)d_out;

  char* ws = (char*)d_ws;
  fp16*  x    = (fp16*) (ws + 0);
  bf16*  h1   = (bf16*) (ws + 67108864);
  bf16*  h2   = (bf16*) (ws + 134217728);
  fp16*  lk   = (fp16*) (ws + 134217728);
  float* lang = (float*)(ws + 236978176);
  bf16*  wb3  = (bf16*) (ws + 236979968);
  bf16*  wb1  = (bf16*) (ws + 237053696);

  setup_pool_kernel<<<2344, 256, 0, stream>>>(sm, w_in, b_in, x, h1,
                                              w_d3, w_d1, wb3, wb1,
                                              act, w_a1, b_a1, w_a2, b_a2, lang);
  conv3x3_mfma<3><<<2048, 512, 0, stream>>>(h1, wb3, b_d3, h2);
  conv3x3_mfma<1><<<2048, 512, 0, stream>>>(h2, wb1, b_d1, h1);
  out_motion_kernel<<<2048, 256, 0, stream>>>(h1, x, w_out, b_out,
                                              w_k, b_k, lang, lk);
  gather_lse_kernel<<<2048, 256, 0, stream>>>(lb, lk, out);
}